// Round 1
// baseline (883.131 us; speedup 1.0000x reference)
//
#include <hip/hip_runtime.h>
#include <hip/hip_bf16.h>
#include <math.h>

#define N_NODES 100000
#define N_EDGES 1600000
#define IN_FEATS 256
#define OUT_FEATS 64
#define NHEAD 4
#define F_TOT 256            // OUT_FEATS * NHEAD
#define ALPHA 0.2f

// ---------------- workspace layout (bytes) ----------------
#define OFF_H    ((size_t)0)                       // 100000*256*4 = 102,400,000
#define OFF_HL   ((size_t)102400000)               // 100000*4*4   = 1,600,000
#define OFF_HR   ((size_t)104000000)               // 1,600,000
#define OFF_CNT  ((size_t)105600000)               // (100001)*4 -> pad 400,128
#define OFF_OFFS ((size_t)106000128)               // 400,128
#define OFF_CUR  ((size_t)106400256)               // 400,128
#define OFF_EID  ((size_t)106800384)               // 1,600,000*4 = 6,400,000
// total ~113.2 MB

// ---------------- GEMM: h = x @ W  (f32) ----------------
#define BM 64
#define BN 64
#define BK 32

__global__ __launch_bounds__(256) void gemm_f32(const float* __restrict__ A,
                                                const float* __restrict__ B,
                                                float* __restrict__ C,
                                                int M, int N, int K) {
  __shared__ float As[BK][BM];   // A transposed in LDS
  __shared__ float Bs[BK][BN];
  const int row0 = blockIdx.x * BM;
  const int col0 = blockIdx.y * BN;
  const int tid = threadIdx.x;
  const int tx = tid & 15;       // 16 cols of thread tiles
  const int ty = tid >> 4;       // 16 rows
  float acc[4][4] = {};

  for (int k0 = 0; k0 < K; k0 += BK) {
    // A tile: 64 rows x 32 cols = 512 float4, 2 per thread
    #pragma unroll
    for (int i = 0; i < 2; ++i) {
      int idx = tid + i * 256;       // 0..511
      int r   = idx >> 3;            // 8 float4 per row
      int c4  = idx & 7;
      int gr  = row0 + r;
      float4 v = make_float4(0.f, 0.f, 0.f, 0.f);
      if (gr < M) v = *(const float4*)&A[(size_t)gr * K + k0 + c4 * 4];
      As[c4 * 4 + 0][r] = v.x;
      As[c4 * 4 + 1][r] = v.y;
      As[c4 * 4 + 2][r] = v.z;
      As[c4 * 4 + 3][r] = v.w;
    }
    // B tile: 32 rows x 64 cols = 512 float4, 2 per thread
    #pragma unroll
    for (int i = 0; i < 2; ++i) {
      int idx = tid + i * 256;
      int r   = idx >> 4;            // 16 float4 per row
      int c4  = idx & 15;
      float4 v = *(const float4*)&B[(size_t)(k0 + r) * N + col0 + c4 * 4];
      *(float4*)&Bs[r][c4 * 4] = v;
    }
    __syncthreads();
    #pragma unroll
    for (int k = 0; k < BK; ++k) {
      float a[4], b[4];
      #pragma unroll
      for (int i = 0; i < 4; ++i) a[i] = As[k][ty * 4 + i];
      #pragma unroll
      for (int j = 0; j < 4; ++j) b[j] = Bs[k][tx * 4 + j];
      #pragma unroll
      for (int i = 0; i < 4; ++i)
        #pragma unroll
        for (int j = 0; j < 4; ++j)
          acc[i][j] = fmaf(a[i], b[j], acc[i][j]);
    }
    __syncthreads();
  }
  #pragma unroll
  for (int i = 0; i < 4; ++i) {
    int gr = row0 + ty * 4 + i;
    if (gr < M) {
      float4 v = make_float4(acc[i][0], acc[i][1], acc[i][2], acc[i][3]);
      *(float4*)&C[(size_t)gr * N + col0 + tx * 4] = v;
    }
  }
}

// ---------------- hl/hr: per-node attention logits ----------------
__global__ __launch_bounds__(256) void hlr_kernel(const float* __restrict__ h,
                                                  const float* __restrict__ a_l,
                                                  const float* __restrict__ a_r,
                                                  float* __restrict__ hl,
                                                  float* __restrict__ hr, int n) {
  int wave = (blockIdx.x * blockDim.x + threadIdx.x) >> 6;
  int lane = threadIdx.x & 63;
  if (wave >= n) return;
  const float4 hv = *(const float4*)&h[(size_t)wave * F_TOT + lane * 4];
  int head = lane >> 4;
  int fb = (lane & 15) * 4;
  const float4 al = *(const float4*)&a_l[head * OUT_FEATS + fb];
  const float4 ar = *(const float4*)&a_r[head * OUT_FEATS + fb];
  float pl = hv.x * al.x + hv.y * al.y + hv.z * al.z + hv.w * al.w;
  float pr = hv.x * ar.x + hv.y * ar.y + hv.z * ar.z + hv.w * ar.w;
  #pragma unroll
  for (int d = 8; d >= 1; d >>= 1) {
    pl += __shfl_xor(pl, d);
    pr += __shfl_xor(pr, d);
  }
  if ((lane & 15) == 0) {
    hl[wave * NHEAD + head] = pl;
    hr[wave * NHEAD + head] = pr;
  }
}

// ---------------- CSR build ----------------
__global__ void hist_kernel(const int* __restrict__ row, int* __restrict__ counts, int E) {
  int i = blockIdx.x * blockDim.x + threadIdx.x;
  if (i < E) atomicAdd(&counts[row[i]], 1);
}

__global__ __launch_bounds__(1024) void scan_kernel(const int* __restrict__ counts,
                                                    int* __restrict__ offsets,
                                                    int* __restrict__ cursor, int n) {
  __shared__ int wsum[16];
  __shared__ int sChunk;
  const int tid = threadIdx.x;
  const int lane = tid & 63;
  const int wid = tid >> 6;
  if (tid == 0) sChunk = 0;
  __syncthreads();
  for (int base = 0; base < n; base += 1024) {
    int i = base + tid;
    int v = (i < n) ? counts[i] : 0;
    int inc = v;
    #pragma unroll
    for (int d = 1; d < 64; d <<= 1) {
      int t = __shfl_up(inc, d);
      if (lane >= d) inc += t;
    }
    if (lane == 63) wsum[wid] = inc;
    __syncthreads();
    if (tid < 16) {
      int x = wsum[tid];
      #pragma unroll
      for (int d = 1; d < 16; d <<= 1) {
        int t = __shfl_up(x, d);
        if (tid >= d) x += t;
      }
      wsum[tid] = x;
    }
    __syncthreads();
    int run = sChunk;
    int woff = (wid > 0) ? wsum[wid - 1] : 0;
    int excl = run + woff + inc - v;
    if (i < n) { offsets[i] = excl; cursor[i] = excl; }
    __syncthreads();
    if (tid == 0) sChunk = run + wsum[15];
    __syncthreads();
  }
  if (tid == 0) { offsets[n] = sChunk; cursor[n] = sChunk; }
}

__global__ void scatter_kernel(const int* __restrict__ row, int* __restrict__ cursor,
                               int* __restrict__ eid, int E) {
  int i = blockIdx.x * blockDim.x + threadIdx.x;
  if (i < E) {
    int p = atomicAdd(&cursor[row[i]], 1);
    eid[p] = i;
  }
}

// ---------------- aggregation: wave per node ----------------
__global__ __launch_bounds__(256) void agg_kernel(const float* __restrict__ h,
                                                  const float* __restrict__ hl,
                                                  const float* __restrict__ hr,
                                                  const int* __restrict__ col,
                                                  const int* __restrict__ offsets,
                                                  const int* __restrict__ eid,
                                                  float* __restrict__ out, int n) {
  int node = blockIdx.x * 4 + (threadIdx.x >> 6);
  int lane = threadIdx.x & 63;
  if (node >= n) return;
  const int s = offsets[node];
  const int t = offsets[node + 1];
  const int head = lane >> 4;
  const float hln = hl[node * NHEAD + head];

  // pass 1: segment max (per head, redundantly computed by each lane of group)
  float m = -INFINITY;
  for (int i = s; i < t; ++i) {
    int c = col[eid[i]];
    float sc = hln + hr[c * NHEAD + head];
    sc = sc > 0.f ? sc : ALPHA * sc;
    m = fmaxf(m, sc);
  }
  // pass 2: exp-sum + weighted aggregation
  float denom = 0.f;
  float a0 = 0.f, a1 = 0.f, a2 = 0.f, a3 = 0.f;
  for (int i = s; i < t; ++i) {
    int c = col[eid[i]];
    float sc = hln + hr[c * NHEAD + head];
    sc = sc > 0.f ? sc : ALPHA * sc;
    float w = __expf(sc - m);
    denom += w;
    const float4 hv = *(const float4*)&h[(size_t)c * F_TOT + lane * 4];
    a0 = fmaf(w, hv.x, a0);
    a1 = fmaf(w, hv.y, a1);
    a2 = fmaf(w, hv.z, a2);
    a3 = fmaf(w, hv.w, a3);
  }
  float inv = 1.f / (denom + 1e-16f);
  float4 o = make_float4(a0 * inv, a1 * inv, a2 * inv, a3 * inv);
  *(float4*)&out[(size_t)node * F_TOT + lane * 4] = o;
}

// ---------------- launcher ----------------
extern "C" void kernel_launch(void* const* d_in, const int* in_sizes, int n_in,
                              void* d_out, int out_size, void* d_ws, size_t ws_size,
                              hipStream_t stream) {
  const float* x   = (const float*)d_in[0];
  const float* W   = (const float*)d_in[1];
  const float* a_l = (const float*)d_in[2];
  const float* a_r = (const float*)d_in[3];
  const int*   row = (const int*)d_in[4];
  const int*   col = (const int*)d_in[5];
  float* out = (float*)d_out;

  const int n = in_sizes[0] / IN_FEATS;   // 100000
  const int E = in_sizes[4];              // 1600000

  char* ws = (char*)d_ws;
  float* h       = (float*)(ws + OFF_H);
  float* hl      = (float*)(ws + OFF_HL);
  float* hr      = (float*)(ws + OFF_HR);
  int*   counts  = (int*)(ws + OFF_CNT);
  int*   offsets = (int*)(ws + OFF_OFFS);
  int*   cursor  = (int*)(ws + OFF_CUR);
  int*   eid     = (int*)(ws + OFF_EID);

  // 1. GEMM h = x @ W
  dim3 ggrid((n + BM - 1) / BM, F_TOT / BN);
  gemm_f32<<<ggrid, 256, 0, stream>>>(x, W, h, n, F_TOT, IN_FEATS);

  // 2. hl / hr
  hlr_kernel<<<(n * 64 + 255) / 256, 256, 0, stream>>>(h, a_l, a_r, hl, hr, n);

  // 3. CSR build
  hipMemsetAsync(counts, 0, (size_t)(n + 1) * sizeof(int), stream);
  hist_kernel<<<(E + 255) / 256, 256, 0, stream>>>(row, counts, E);
  scan_kernel<<<1, 1024, 0, stream>>>(counts, offsets, cursor, n);
  scatter_kernel<<<(E + 255) / 256, 256, 0, stream>>>(row, cursor, eid, E);

  // 4. aggregation
  agg_kernel<<<(n + 3) / 4, 256, 0, stream>>>(h, hl, hr, col, offsets, eid, out, n);
}

// Round 2
// 488.893 us; speedup vs baseline: 1.8064x; 1.8064x over previous
//
#include <hip/hip_runtime.h>
#include <hip/hip_bf16.h>
#include <math.h>

#define N_NODES 100000
#define N_EDGES 1600000
#define IN_FEATS 256
#define OUT_FEATS 64
#define NHEAD 4
#define F_TOT 256
#define ALPHA 0.2f

typedef __attribute__((ext_vector_type(8))) short short8;
typedef __attribute__((ext_vector_type(4))) float f32x4;

// ---------------- workspace layout (bytes) ----------------
// hb (h bf16):    0          .. 51,200,000
// xb (x bf16):    51,200,000 .. 102,400,000   [dead after gemm; CSR overlays]
// Wt (bf16):      102,400,000 .. 102,531,072  [dead after gemm]
// hl (f32):       102,531,072 .. 104,131,072
// hr (f32):       104,131,072 .. 105,731,072
// CSR arrays overlay the xb region (gemm completes before CSR build starts):
#define OFF_HB   ((size_t)0)
#define OFF_XB   ((size_t)51200000)
#define OFF_WT   ((size_t)102400000)
#define OFF_HL   ((size_t)102531072)
#define OFF_HR   ((size_t)104131072)
#define OFF_CNT  (OFF_XB)                    // (n+1) ints, pad 400,128
#define OFF_OFFS (OFF_XB + 400128)
#define OFF_CUR  (OFF_XB + 800256)
#define OFF_CSORT (OFF_XB + 1200384)         // E ints = 6.4 MB
#define OFF_BSUM (OFF_XB + 7600384)          // ~100 ints

// ---------------- casts ----------------
__global__ __launch_bounds__(256) void cast_x_kernel(const float* __restrict__ x,
                                                     ushort* __restrict__ xb, int total8) {
  int i = blockIdx.x * blockDim.x + threadIdx.x;
  if (i >= total8) return;
  const float4 v0 = ((const float4*)x)[(size_t)i * 2];
  const float4 v1 = ((const float4*)x)[(size_t)i * 2 + 1];
  union { ushort u[8]; short8 v; } r;
  float f[8] = {v0.x, v0.y, v0.z, v0.w, v1.x, v1.y, v1.z, v1.w};
  #pragma unroll
  for (int k = 0; k < 8; ++k) {
    __hip_bfloat16 b = __float2bfloat16(f[k]);
    r.u[k] = *(ushort*)&b;
  }
  ((short8*)xb)[i] = r.v;
}

__global__ __launch_bounds__(256) void castT_W_kernel(const float* __restrict__ W,
                                                      ushort* __restrict__ Wt) {
  int t = threadIdx.x;  // output row (n), 0..255
  for (int k = 0; k < IN_FEATS; ++k) {
    __hip_bfloat16 b = __float2bfloat16(W[(size_t)k * F_TOT + t]);
    Wt[(size_t)t * IN_FEATS + k] = *(ushort*)&b;
  }
}

// ---------------- MFMA GEMM: h = x @ W (bf16 in, f32 acc) ----------------
// BM=128, BN=128, BK=64; 256 threads = 4 waves in 2x2; wave owns 64x64.
// Fused epilogue: writes h (bf16) and exact hl/hr from f32 accumulators.
#define GBM 128
#define GBN 128
#define GBK 64

__global__ __launch_bounds__(256) void gemm_bf16(const ushort* __restrict__ A,   // xb [M][256]
                                                 const ushort* __restrict__ Bt,  // Wt [N][256]
                                                 ushort* __restrict__ hb,
                                                 const float* __restrict__ a_l,
                                                 const float* __restrict__ a_r,
                                                 float* __restrict__ hl,
                                                 float* __restrict__ hr, int M) {
  __shared__ __align__(16) ushort As[GBM][GBK + 8];  // pad: stride 144B -> 2-way max
  __shared__ __align__(16) ushort Bs[GBN][GBK + 8];
  const int row0 = blockIdx.x * GBM;
  const int col0 = blockIdx.y * GBN;
  const int tid = threadIdx.x;
  const int lane = tid & 63;
  const int wid = tid >> 6;
  const int wr = wid >> 1, wc = wid & 1;
  const int lr = lane & 15;
  const int kq = lane >> 4;        // 0..3

  f32x4 acc[4][4];
  #pragma unroll
  for (int i = 0; i < 4; ++i)
    #pragma unroll
    for (int j = 0; j < 4; ++j) acc[i][j] = (f32x4)(0.f);

  for (int k0 = 0; k0 < IN_FEATS; k0 += GBK) {
    // stage A: 128 rows x 64 cols bf16 = 1024 chunks of 16B; 4 per thread
    short8 ar[4], br[4];
    #pragma unroll
    for (int ii = 0; ii < 4; ++ii) {
      int ch = ii * 256 + tid;
      int r = ch >> 3, cc = ch & 7;       // 8 chunks per 64-col row
      int gr = row0 + r;
      short8 v = (short8)(0);
      if (gr < M) v = *(const short8*)&A[(size_t)gr * IN_FEATS + k0 + cc * 8];
      ar[ii] = v;
      br[ii] = *(const short8*)&Bt[(size_t)(col0 + r) * IN_FEATS + k0 + cc * 8];
    }
    __syncthreads();
    #pragma unroll
    for (int ii = 0; ii < 4; ++ii) {
      int ch = ii * 256 + tid;
      int r = ch >> 3, cc = ch & 7;
      *(short8*)&As[r][cc * 8] = ar[ii];
      *(short8*)&Bs[r][cc * 8] = br[ii];
    }
    __syncthreads();
    #pragma unroll
    for (int ks = 0; ks < 2; ++ks) {
      const int kb = ks * 32 + kq * 8;
      short8 af[4], bf[4];
      #pragma unroll
      for (int i = 0; i < 4; ++i) af[i] = *(const short8*)&As[wr * 64 + i * 16 + lr][kb];
      #pragma unroll
      for (int j = 0; j < 4; ++j) bf[j] = *(const short8*)&Bs[wc * 64 + j * 16 + lr][kb];
      #pragma unroll
      for (int i = 0; i < 4; ++i)
        #pragma unroll
        for (int j = 0; j < 4; ++j)
          acc[i][j] = __builtin_amdgcn_mfma_f32_16x16x32_bf16(af[i], bf[j], acc[i][j], 0, 0, 0);
    }
  }

  // epilogue 1: write h as bf16.  C mapping: col=lane&15, row=(lane>>4)*4+reg
  #pragma unroll
  for (int i = 0; i < 4; ++i) {
    int rbase = row0 + wr * 64 + i * 16 + kq * 4;
    #pragma unroll
    for (int j = 0; j < 4; ++j) {
      int cc = col0 + wc * 64 + j * 16 + lr;
      #pragma unroll
      for (int reg = 0; reg < 4; ++reg) {
        int r = rbase + reg;
        if (r < M) {
          __hip_bfloat16 b = __float2bfloat16(acc[i][j][reg]);
          hb[(size_t)r * F_TOT + cc] = *(ushort*)&b;
        }
      }
    }
  }

  // epilogue 2: hl/hr for this wave's head (wave's 64 cols == one head)
  const int head = blockIdx.y * 2 + wc;
  float alv[4], arv[4];
  #pragma unroll
  for (int j = 0; j < 4; ++j) {
    alv[j] = a_l[head * OUT_FEATS + j * 16 + lr];
    arv[j] = a_r[head * OUT_FEATS + j * 16 + lr];
  }
  #pragma unroll
  for (int i = 0; i < 4; ++i) {
    #pragma unroll
    for (int reg = 0; reg < 4; ++reg) {
      float pl = 0.f, pr = 0.f;
      #pragma unroll
      for (int j = 0; j < 4; ++j) {
        pl = fmaf(acc[i][j][reg], alv[j], pl);
        pr = fmaf(acc[i][j][reg], arv[j], pr);
      }
      #pragma unroll
      for (int d = 8; d >= 1; d >>= 1) {
        pl += __shfl_xor(pl, d);
        pr += __shfl_xor(pr, d);
      }
      if (lr == 0) {
        int r = row0 + wr * 64 + i * 16 + kq * 4 + reg;
        if (r < M) {
          hl[r * NHEAD + head] = pl;
          hr[r * NHEAD + head] = pr;
        }
      }
    }
  }
}

// ---------------- CSR build ----------------
__global__ void hist_kernel(const int* __restrict__ row, int* __restrict__ counts, int E) {
  int i = blockIdx.x * blockDim.x + threadIdx.x;
  if (i < E) atomicAdd(&counts[row[i]], 1);
}

// per-block exclusive scan of 1024 elements
__global__ __launch_bounds__(1024) void scan1_kernel(const int* __restrict__ counts,
                                                     int* __restrict__ offsets,
                                                     int* __restrict__ bsum, int n) {
  __shared__ int wsum[16];
  const int tid = threadIdx.x;
  const int lane = tid & 63;
  const int wid = tid >> 6;
  int i = blockIdx.x * 1024 + tid;
  int v = (i < n) ? counts[i] : 0;
  int inc = v;
  #pragma unroll
  for (int d = 1; d < 64; d <<= 1) {
    int t = __shfl_up(inc, d);
    if (lane >= d) inc += t;
  }
  if (lane == 63) wsum[wid] = inc;
  __syncthreads();
  if (tid < 16) {
    int x = wsum[tid];
    #pragma unroll
    for (int d = 1; d < 16; d <<= 1) {
      int t = __shfl_up(x, d);
      if (tid >= d) x += t;
    }
    wsum[tid] = x;
  }
  __syncthreads();
  int excl = ((wid > 0) ? wsum[wid - 1] : 0) + inc - v;
  if (i < n) offsets[i] = excl;
  if (tid == 0) bsum[blockIdx.x] = wsum[15];
}

// single-block scan of block sums (nblk <= 128)
__global__ __launch_bounds__(128) void scan2_kernel(int* __restrict__ bsum, int nblk) {
  __shared__ int s0;
  const int tid = threadIdx.x;
  const int lane = tid & 63;
  const int wid = tid >> 6;
  int v = (tid < nblk) ? bsum[tid] : 0;
  int inc = v;
  #pragma unroll
  for (int d = 1; d < 64; d <<= 1) {
    int t = __shfl_up(inc, d);
    if (lane >= d) inc += t;
  }
  if (wid == 0 && lane == 63) s0 = inc;
  __syncthreads();
  if (wid == 1) inc += s0;
  if (tid < nblk) bsum[tid] = inc - v;      // exclusive
  if (tid == nblk - 1) bsum[nblk] = inc;    // total
}

__global__ __launch_bounds__(256) void scan3_kernel(int* __restrict__ offsets,
                                                    int* __restrict__ cursor,
                                                    const int* __restrict__ bsum,
                                                    int n, int nblk) {
  int i = blockIdx.x * blockDim.x + threadIdx.x;
  if (i < n) {
    int off = offsets[i] + bsum[i >> 10];
    offsets[i] = off;
    cursor[i] = off;
  }
  if (i == 0) offsets[n] = bsum[nblk];
}

__global__ void scatter_kernel(const int* __restrict__ row, const int* __restrict__ col,
                               int* __restrict__ cursor, int* __restrict__ col_sorted, int E) {
  int i = blockIdx.x * blockDim.x + threadIdx.x;
  if (i < E) {
    int p = atomicAdd(&cursor[row[i]], 1);
    col_sorted[p] = col[i];
  }
}

// ---------------- aggregation: wave per node, online softmax, bf16 h ----------------
__global__ __launch_bounds__(256) void agg_kernel(const ushort* __restrict__ hb,
                                                  const float* __restrict__ hl,
                                                  const float* __restrict__ hr,
                                                  const int* __restrict__ col_sorted,
                                                  const int* __restrict__ offsets,
                                                  float* __restrict__ out, int n) {
  int node = blockIdx.x * 4 + (threadIdx.x >> 6);
  int lane = threadIdx.x & 63;
  if (node >= n) return;
  const int s = offsets[node];
  const int t = offsets[node + 1];
  const int head = lane >> 4;
  const float hln = hl[node * NHEAD + head];

  float m = -INFINITY, denom = 0.f;
  float a0 = 0.f, a1 = 0.f, a2 = 0.f, a3 = 0.f;
  for (int i = s; i < t; ++i) {
    int c = col_sorted[i];
    float sc = hln + hr[c * NHEAD + head];
    sc = sc > 0.f ? sc : ALPHA * sc;
    float nm = fmaxf(m, sc);
    float f = __expf(m - nm);     // 1 if max unchanged; 0 on first edge
    float w = __expf(sc - nm);
    const ushort4 hv = *(const ushort4*)&hb[(size_t)c * F_TOT + lane * 4];
    float h0 = __uint_as_float((uint)hv.x << 16);
    float h1 = __uint_as_float((uint)hv.y << 16);
    float h2 = __uint_as_float((uint)hv.z << 16);
    float h3 = __uint_as_float((uint)hv.w << 16);
    denom = fmaf(denom, f, w);
    a0 = fmaf(a0, f, w * h0);
    a1 = fmaf(a1, f, w * h1);
    a2 = fmaf(a2, f, w * h2);
    a3 = fmaf(a3, f, w * h3);
    m = nm;
  }
  float inv = 1.f / (denom + 1e-16f);
  float4 o = make_float4(a0 * inv, a1 * inv, a2 * inv, a3 * inv);
  *(float4*)&out[(size_t)node * F_TOT + lane * 4] = o;
}

// ---------------- launcher ----------------
extern "C" void kernel_launch(void* const* d_in, const int* in_sizes, int n_in,
                              void* d_out, int out_size, void* d_ws, size_t ws_size,
                              hipStream_t stream) {
  const float* x   = (const float*)d_in[0];
  const float* W   = (const float*)d_in[1];
  const float* a_l = (const float*)d_in[2];
  const float* a_r = (const float*)d_in[3];
  const int*   row = (const int*)d_in[4];
  const int*   col = (const int*)d_in[5];
  float* out = (float*)d_out;

  const int n = in_sizes[0] / IN_FEATS;   // 100000
  const int E = in_sizes[4];              // 1600000

  char* ws = (char*)d_ws;
  ushort* hb      = (ushort*)(ws + OFF_HB);
  ushort* xb      = (ushort*)(ws + OFF_XB);
  ushort* Wt      = (ushort*)(ws + OFF_WT);
  float*  hl      = (float*)(ws + OFF_HL);
  float*  hr      = (float*)(ws + OFF_HR);
  int* counts     = (int*)(ws + OFF_CNT);
  int* offsets    = (int*)(ws + OFF_OFFS);
  int* cursor     = (int*)(ws + OFF_CUR);
  int* col_sorted = (int*)(ws + OFF_CSORT);
  int* bsum       = (int*)(ws + OFF_BSUM);

  // 1. casts
  int total8 = n * IN_FEATS / 8;
  cast_x_kernel<<<(total8 + 255) / 256, 256, 0, stream>>>(x, xb, total8);
  castT_W_kernel<<<1, 256, 0, stream>>>(W, Wt);

  // 2. GEMM + fused hl/hr epilogue
  dim3 ggrid((n + GBM - 1) / GBM, F_TOT / GBN);
  gemm_bf16<<<ggrid, 256, 0, stream>>>(xb, Wt, hb, a_l, a_r, hl, hr, n);

  // 3. CSR build (arrays overlay xb region -> must come after gemm)
  hipMemsetAsync(counts, 0, (size_t)(n + 1) * sizeof(int), stream);
  hist_kernel<<<(E + 255) / 256, 256, 0, stream>>>(row, counts, E);
  int nblk = (n + 1023) / 1024;
  scan1_kernel<<<nblk, 1024, 0, stream>>>(counts, offsets, bsum, n);
  scan2_kernel<<<1, 128, 0, stream>>>(bsum, nblk);
  scan3_kernel<<<(n + 255) / 256, 256, 0, stream>>>(offsets, cursor, bsum, n, nblk);
  scatter_kernel<<<(E + 255) / 256, 256, 0, stream>>>(row, col, cursor, col_sorted, E);

  // 4. aggregation (online softmax, bf16 gather)
  agg_kernel<<<(n + 3) / 4, 256, 0, stream>>>(hb, hl, hr, col_sorted, offsets, out, n);
}

// Round 3
// 416.587 us; speedup vs baseline: 2.1199x; 1.1736x over previous
//
#include <hip/hip_runtime.h>
#include <hip/hip_bf16.h>
#include <math.h>

#define N_NODES 100000
#define N_EDGES 1600000
#define IN_FEATS 256
#define OUT_FEATS 64
#define NHEAD 4
#define F_TOT 256
#define ALPHA 0.2f

typedef __attribute__((ext_vector_type(8))) short short8;
typedef __attribute__((ext_vector_type(4))) float f32x4;

// ---------------- workspace layout (bytes) ----------------
#define OFF_HB    ((size_t)0)            // 100000*256*2 = 51,200,000
#define OFF_HL    ((size_t)51200000)     // 1,600,000
#define OFF_HR    ((size_t)52800000)     // 1,600,000
#define OFF_CNT   ((size_t)54400000)     // 400,128
#define OFF_OFFS  ((size_t)54800128)     // 400,128
#define OFF_CUR   ((size_t)55200256)     // 400,128
#define OFF_CSORT ((size_t)55600384)     // 6,400,000
#define OFF_BSUM  ((size_t)62000384)     // 512
#define OFF_WT    ((size_t)62000896)     // 131,072
// total ~62.2 MB

__device__ inline float bf2f(ushort u) { return __uint_as_float((uint)u << 16); }
__device__ inline ushort f2bf(float f) {
  __hip_bfloat16 b = __float2bfloat16(f);
  return *(ushort*)&b;
}

// ---------------- W transpose+cast: Wt[n][k] = bf16(W[k][n]) ----------------
__global__ __launch_bounds__(256) void castT_W_kernel(const float* __restrict__ W,
                                                      ushort* __restrict__ Wt) {
  __shared__ float s[64][65];
  const int bi = blockIdx.x & 3;   // n block
  const int bj = blockIdx.x >> 2;  // k block
  const int tid = threadIdx.x;
  const int n0 = bi * 64, k0 = bj * 64;
  #pragma unroll
  for (int it = 0; it < 16; ++it) {
    int idx = it * 256 + tid;
    int r = idx >> 6;        // k within tile
    int c = idx & 63;        // n within tile
    s[c][r] = W[(size_t)(k0 + r) * F_TOT + n0 + c];
  }
  __syncthreads();
  #pragma unroll
  for (int it = 0; it < 16; ++it) {
    int idx = it * 256 + tid;
    int nn = idx >> 6;       // n within tile
    int kk = idx & 63;       // k within tile
    Wt[(size_t)(n0 + nn) * IN_FEATS + k0 + kk] = f2bf(s[nn][kk]);
  }
}

// ---------------- MFMA GEMM: h = x @ W (f32 x cast in staging) ----------------
#define GBM 128
#define GBN 128
#define GBK 64

__global__ __launch_bounds__(256) void gemm_bf16(const float* __restrict__ X,    // [M][256] f32
                                                 const ushort* __restrict__ Bt,  // Wt [N][256] bf16
                                                 ushort* __restrict__ hb,
                                                 const float* __restrict__ a_l,
                                                 const float* __restrict__ a_r,
                                                 float* __restrict__ hl,
                                                 float* __restrict__ hr, int M) {
  __shared__ __align__(16) ushort As[GBM][GBK + 8];
  __shared__ __align__(16) ushort Bs[GBN][GBK + 8];
  const int row0 = blockIdx.x * GBM;
  const int col0 = blockIdx.y * GBN;
  const int tid = threadIdx.x;
  const int lane = tid & 63;
  const int wid = tid >> 6;
  const int wr = wid >> 1, wc = wid & 1;
  const int lr = lane & 15;
  const int kq = lane >> 4;

  f32x4 acc[4][4];
  #pragma unroll
  for (int i = 0; i < 4; ++i)
    #pragma unroll
    for (int j = 0; j < 4; ++j) acc[i][j] = (f32x4)(0.f);

  for (int k0 = 0; k0 < IN_FEATS; k0 += GBK) {
    short8 ar[4], br[4];
    #pragma unroll
    for (int ii = 0; ii < 4; ++ii) {
      int ch = ii * 256 + tid;
      int r = ch >> 3, cc = ch & 7;
      int gr = row0 + r;
      short8 v = (short8)(0);
      if (gr < M) {
        const float4 f0 = *(const float4*)&X[(size_t)gr * IN_FEATS + k0 + cc * 8];
        const float4 f1 = *(const float4*)&X[(size_t)gr * IN_FEATS + k0 + cc * 8 + 4];
        union { ushort u[8]; short8 s; } t;
        t.u[0] = f2bf(f0.x); t.u[1] = f2bf(f0.y); t.u[2] = f2bf(f0.z); t.u[3] = f2bf(f0.w);
        t.u[4] = f2bf(f1.x); t.u[5] = f2bf(f1.y); t.u[6] = f2bf(f1.z); t.u[7] = f2bf(f1.w);
        v = t.s;
      }
      ar[ii] = v;
      br[ii] = *(const short8*)&Bt[(size_t)(col0 + r) * IN_FEATS + k0 + cc * 8];
    }
    __syncthreads();
    #pragma unroll
    for (int ii = 0; ii < 4; ++ii) {
      int ch = ii * 256 + tid;
      int r = ch >> 3, cc = ch & 7;
      *(short8*)&As[r][cc * 8] = ar[ii];
      *(short8*)&Bs[r][cc * 8] = br[ii];
    }
    __syncthreads();
    #pragma unroll
    for (int ks = 0; ks < 2; ++ks) {
      const int kb = ks * 32 + kq * 8;
      short8 af[4], bf[4];
      #pragma unroll
      for (int i = 0; i < 4; ++i) af[i] = *(const short8*)&As[wr * 64 + i * 16 + lr][kb];
      #pragma unroll
      for (int j = 0; j < 4; ++j) bf[j] = *(const short8*)&Bs[wc * 64 + j * 16 + lr][kb];
      #pragma unroll
      for (int i = 0; i < 4; ++i)
        #pragma unroll
        for (int j = 0; j < 4; ++j)
          acc[i][j] = __builtin_amdgcn_mfma_f32_16x16x32_bf16(af[i], bf[j], acc[i][j], 0, 0, 0);
    }
  }

  // epilogue 1: write h bf16.  C mapping: col=lane&15, row=(lane>>4)*4+reg
  #pragma unroll
  for (int i = 0; i < 4; ++i) {
    int rbase = row0 + wr * 64 + i * 16 + kq * 4;
    #pragma unroll
    for (int j = 0; j < 4; ++j) {
      int cc = col0 + wc * 64 + j * 16 + lr;
      #pragma unroll
      for (int reg = 0; reg < 4; ++reg) {
        int r = rbase + reg;
        if (r < M) hb[(size_t)r * F_TOT + cc] = f2bf(acc[i][j][reg]);
      }
    }
  }

  // epilogue 2: hl/hr (wave's 64 cols == one head)
  const int head = blockIdx.y * 2 + wc;
  float alv[4], arv[4];
  #pragma unroll
  for (int j = 0; j < 4; ++j) {
    alv[j] = a_l[head * OUT_FEATS + j * 16 + lr];
    arv[j] = a_r[head * OUT_FEATS + j * 16 + lr];
  }
  #pragma unroll
  for (int i = 0; i < 4; ++i) {
    #pragma unroll
    for (int reg = 0; reg < 4; ++reg) {
      float pl = 0.f, pr = 0.f;
      #pragma unroll
      for (int j = 0; j < 4; ++j) {
        pl = fmaf(acc[i][j][reg], alv[j], pl);
        pr = fmaf(acc[i][j][reg], arv[j], pr);
      }
      #pragma unroll
      for (int d = 8; d >= 1; d >>= 1) {
        pl += __shfl_xor(pl, d);
        pr += __shfl_xor(pr, d);
      }
      if (lr == 0) {
        int r = row0 + wr * 64 + i * 16 + kq * 4 + reg;
        if (r < M) {
          hl[r * NHEAD + head] = pl;
          hr[r * NHEAD + head] = pr;
        }
      }
    }
  }
}

// ---------------- CSR build ----------------
__global__ void hist_kernel(const int* __restrict__ row, int* __restrict__ counts, int E) {
  int i = blockIdx.x * blockDim.x + threadIdx.x;
  if (i < E) atomicAdd(&counts[row[i]], 1);
}

__global__ __launch_bounds__(1024) void scan1_kernel(const int* __restrict__ counts,
                                                     int* __restrict__ offsets,
                                                     int* __restrict__ bsum, int n) {
  __shared__ int wsum[16];
  const int tid = threadIdx.x;
  const int lane = tid & 63;
  const int wid = tid >> 6;
  int i = blockIdx.x * 1024 + tid;
  int v = (i < n) ? counts[i] : 0;
  int inc = v;
  #pragma unroll
  for (int d = 1; d < 64; d <<= 1) {
    int t = __shfl_up(inc, d);
    if (lane >= d) inc += t;
  }
  if (lane == 63) wsum[wid] = inc;
  __syncthreads();
  if (tid < 16) {
    int x = wsum[tid];
    #pragma unroll
    for (int d = 1; d < 16; d <<= 1) {
      int t = __shfl_up(x, d);
      if (tid >= d) x += t;
    }
    wsum[tid] = x;
  }
  __syncthreads();
  int excl = ((wid > 0) ? wsum[wid - 1] : 0) + inc - v;
  if (i < n) offsets[i] = excl;
  if (tid == 0) bsum[blockIdx.x] = wsum[15];
}

__global__ __launch_bounds__(128) void scan2_kernel(int* __restrict__ bsum, int nblk) {
  __shared__ int s0;
  const int tid = threadIdx.x;
  const int lane = tid & 63;
  const int wid = tid >> 6;
  int v = (tid < nblk) ? bsum[tid] : 0;
  int inc = v;
  #pragma unroll
  for (int d = 1; d < 64; d <<= 1) {
    int t = __shfl_up(inc, d);
    if (lane >= d) inc += t;
  }
  if (wid == 0 && lane == 63) s0 = inc;
  __syncthreads();
  if (wid == 1) inc += s0;
  if (tid < nblk) bsum[tid] = inc - v;
  if (tid == nblk - 1) bsum[nblk] = inc;
}

__global__ __launch_bounds__(256) void scan3_kernel(int* __restrict__ offsets,
                                                    int* __restrict__ cursor,
                                                    const int* __restrict__ bsum,
                                                    int n, int nblk) {
  int i = blockIdx.x * blockDim.x + threadIdx.x;
  if (i < n) {
    int off = offsets[i] + bsum[i >> 10];
    offsets[i] = off;
    cursor[i] = off;
  }
  if (i == 0) offsets[n] = bsum[nblk];
}

__global__ void scatter_kernel(const int* __restrict__ row, const int* __restrict__ col,
                               int* __restrict__ cursor, int* __restrict__ col_sorted, int E) {
  int i = blockIdx.x * blockDim.x + threadIdx.x;
  if (i < E) {
    int p = atomicAdd(&cursor[row[i]], 1);
    col_sorted[p] = col[i];
  }
}

// ---------------- aggregation: wave/node, 2-phase (parallel max, fixed-m accumulate) ----------------
__global__ __launch_bounds__(256) void agg_kernel(const ushort* __restrict__ hb,
                                                  const float* __restrict__ hl,
                                                  const float* __restrict__ hr,
                                                  const int* __restrict__ col_sorted,
                                                  const int* __restrict__ offsets,
                                                  float* __restrict__ out, int n) {
  int node = blockIdx.x * 4 + (threadIdx.x >> 6);
  int lane = threadIdx.x & 63;
  if (node >= n) return;
  const int s = offsets[node];
  const int t = offsets[node + 1];
  const int head = lane >> 4;
  const int li = lane & 15;
  const float hln = hl[node * NHEAD + head];

  // phase 1: parallel max of hr[col] (LeakyReLU monotone => max commutes)
  float mx = -INFINITY;
  for (int i = s + li; i < t; i += 16) {
    int c = col_sorted[i];
    mx = fmaxf(mx, hr[c * NHEAD + head]);
  }
  #pragma unroll
  for (int d = 1; d < 16; d <<= 1) mx = fmaxf(mx, __shfl_xor(mx, d));
  float e = hln + mx;
  const float m = e > 0.f ? e : ALPHA * e;   // -inf for empty segment

  // phase 2: fixed-m accumulate, 4-wide unroll (independent gathers in flight)
  float denom = 0.f;
  float a0 = 0.f, a1 = 0.f, a2 = 0.f, a3 = 0.f;
  int i = s;
  for (; i + 3 < t; i += 4) {
    const int c0 = col_sorted[i], c1 = col_sorted[i + 1];
    const int c2 = col_sorted[i + 2], c3 = col_sorted[i + 3];
    const float g0 = hr[c0 * NHEAD + head], g1 = hr[c1 * NHEAD + head];
    const float g2 = hr[c2 * NHEAD + head], g3 = hr[c3 * NHEAD + head];
    const ushort4 v0 = *(const ushort4*)&hb[(size_t)c0 * F_TOT + lane * 4];
    const ushort4 v1 = *(const ushort4*)&hb[(size_t)c1 * F_TOT + lane * 4];
    const ushort4 v2 = *(const ushort4*)&hb[(size_t)c2 * F_TOT + lane * 4];
    const ushort4 v3 = *(const ushort4*)&hb[(size_t)c3 * F_TOT + lane * 4];
    float e0 = hln + g0; e0 = e0 > 0.f ? e0 : ALPHA * e0;
    float e1 = hln + g1; e1 = e1 > 0.f ? e1 : ALPHA * e1;
    float e2 = hln + g2; e2 = e2 > 0.f ? e2 : ALPHA * e2;
    float e3 = hln + g3; e3 = e3 > 0.f ? e3 : ALPHA * e3;
    const float w0 = __expf(e0 - m), w1 = __expf(e1 - m);
    const float w2 = __expf(e2 - m), w3 = __expf(e3 - m);
    denom += (w0 + w1) + (w2 + w3);
    a0 = fmaf(w0, bf2f(v0.x), a0); a1 = fmaf(w0, bf2f(v0.y), a1);
    a2 = fmaf(w0, bf2f(v0.z), a2); a3 = fmaf(w0, bf2f(v0.w), a3);
    a0 = fmaf(w1, bf2f(v1.x), a0); a1 = fmaf(w1, bf2f(v1.y), a1);
    a2 = fmaf(w1, bf2f(v1.z), a2); a3 = fmaf(w1, bf2f(v1.w), a3);
    a0 = fmaf(w2, bf2f(v2.x), a0); a1 = fmaf(w2, bf2f(v2.y), a1);
    a2 = fmaf(w2, bf2f(v2.z), a2); a3 = fmaf(w2, bf2f(v2.w), a3);
    a0 = fmaf(w3, bf2f(v3.x), a0); a1 = fmaf(w3, bf2f(v3.y), a1);
    a2 = fmaf(w3, bf2f(v3.z), a2); a3 = fmaf(w3, bf2f(v3.w), a3);
  }
  for (; i < t; ++i) {
    const int c = col_sorted[i];
    const float g = hr[c * NHEAD + head];
    const ushort4 v = *(const ushort4*)&hb[(size_t)c * F_TOT + lane * 4];
    float ee = hln + g; ee = ee > 0.f ? ee : ALPHA * ee;
    const float w = __expf(ee - m);
    denom += w;
    a0 = fmaf(w, bf2f(v.x), a0); a1 = fmaf(w, bf2f(v.y), a1);
    a2 = fmaf(w, bf2f(v.z), a2); a3 = fmaf(w, bf2f(v.w), a3);
  }
  const float inv = 1.f / (denom + 1e-16f);
  float4 o = make_float4(a0 * inv, a1 * inv, a2 * inv, a3 * inv);
  *(float4*)&out[(size_t)node * F_TOT + lane * 4] = o;
}

// ---------------- launcher ----------------
extern "C" void kernel_launch(void* const* d_in, const int* in_sizes, int n_in,
                              void* d_out, int out_size, void* d_ws, size_t ws_size,
                              hipStream_t stream) {
  const float* x   = (const float*)d_in[0];
  const float* W   = (const float*)d_in[1];
  const float* a_l = (const float*)d_in[2];
  const float* a_r = (const float*)d_in[3];
  const int*   row = (const int*)d_in[4];
  const int*   col = (const int*)d_in[5];
  float* out = (float*)d_out;

  const int n = in_sizes[0] / IN_FEATS;   // 100000
  const int E = in_sizes[4];              // 1600000

  char* ws = (char*)d_ws;
  ushort* hb      = (ushort*)(ws + OFF_HB);
  float*  hl      = (float*)(ws + OFF_HL);
  float*  hr      = (float*)(ws + OFF_HR);
  int* counts     = (int*)(ws + OFF_CNT);
  int* offsets    = (int*)(ws + OFF_OFFS);
  int* cursor     = (int*)(ws + OFF_CUR);
  int* col_sorted = (int*)(ws + OFF_CSORT);
  int* bsum       = (int*)(ws + OFF_BSUM);
  ushort* Wt      = (ushort*)(ws + OFF_WT);

  // 1. W transpose+cast (16 blocks of 64x64 tiles)
  castT_W_kernel<<<16, 256, 0, stream>>>(W, Wt);

  // 2. GEMM (reads f32 x, converts in staging) + fused hl/hr epilogue
  dim3 ggrid((n + GBM - 1) / GBM, F_TOT / GBN);
  gemm_bf16<<<ggrid, 256, 0, stream>>>(x, Wt, hb, a_l, a_r, hl, hr, n);

  // 3. CSR build
  hipMemsetAsync(counts, 0, (size_t)(n + 1) * sizeof(int), stream);
  hist_kernel<<<(E + 255) / 256, 256, 0, stream>>>(row, counts, E);
  int nblk = (n + 1023) / 1024;
  scan1_kernel<<<nblk, 1024, 0, stream>>>(counts, offsets, bsum, n);
  scan2_kernel<<<1, 128, 0, stream>>>(bsum, nblk);
  scan3_kernel<<<(n + 255) / 256, 256, 0, stream>>>(offsets, cursor, bsum, n, nblk);
  scatter_kernel<<<(E + 255) / 256, 256, 0, stream>>>(row, col, cursor, col_sorted, E);

  // 4. aggregation
  agg_kernel<<<(n + 3) / 4, 256, 0, stream>>>(hb, hl, hr, col_sorted, offsets, out, n);
}